// Round 1
// baseline (1214.267 us; speedup 1.0000x reference)
//
#include <hip/hip_runtime.h>
#include <math.h>

#define NB 64
#define NS 256
#define ND 64
#define NH2 64
#define NH 128

// d_out layout (floats):
// 0: out_c[64*3]; 192: rx[64]; 256: ry[64]; 320: ex[64]; 384: ey[64];
// 448: out_c_f[64*3]; 640: prob1[64*3]; 832: prob2[64*3]   (total 1024)

// ---------------- K1: mlp11 for x,y + norms + out_c chain + prob1 ----------------
__global__ __launch_bounds__(256) void k1_mlp(
    const float* __restrict__ x, const float* __restrict__ y,
    const float* __restrict__ w11_1, const float* __restrict__ b11_1,
    const float* __restrict__ w11_2, const float* __restrict__ b11_2,
    const float* __restrict__ w12_1, const float* __restrict__ b12_1,
    const float* __restrict__ w12_2, const float* __restrict__ b12_2,
    const float* __restrict__ wc1, const float* __restrict__ bc1,
    float* __restrict__ out_x, float* __restrict__ out_y,
    float* __restrict__ norms, float* __restrict__ dout)
{
    const int b = blockIdx.x;
    const int n = threadIdx.x;
    const int lane = n & 63, wv = n >> 6;

    __shared__ float s_part[4][NH2];
    __shared__ float s_mean[NH2];
    __shared__ float s_sc[4][4];
    __shared__ float s_outc[3];

    float ss_x = 0.f, ss_y = 0.f, ss_ox = 0.f, ss_oy = 0.f;

    const float* xr = x + ((size_t)b*NS + n)*ND;
    const float* yr = y + ((size_t)b*NS + n)*ND;
    float* oxp = out_x + ((size_t)b*NS + n)*NH2;
    float* oyp = out_y + ((size_t)b*NS + n)*NH2;

    float h[NH2], o[NH2];

    // ---- x through mlp11 ----
    #pragma unroll
    for (int j=0;j<NH2;j++) h[j] = b11_1[j];
    for (int k=0;k<ND;k++){
        float xk = xr[k];
        ss_x += xk*xk;
        const float* wr = w11_1 + k*NH2;
        #pragma unroll
        for (int j=0;j<NH2;j++) h[j] += xk*wr[j];
    }
    #pragma unroll
    for (int j=0;j<NH2;j++) h[j] = fmaxf(h[j],0.f);
    #pragma unroll
    for (int j=0;j<NH2;j++) o[j] = b11_2[j];
    #pragma unroll
    for (int k=0;k<NH2;k++){
        float hk = h[k];
        const float* wr = w11_2 + k*NH2;
        #pragma unroll
        for (int j=0;j<NH2;j++) o[j] += hk*wr[j];
    }
    #pragma unroll
    for (int j=0;j<NH2;j++){ oxp[j]=o[j]; ss_ox += o[j]*o[j]; }

    // ---- y through mlp11 (reuse h,o; o ends as oy) ----
    #pragma unroll
    for (int j=0;j<NH2;j++) h[j] = b11_1[j];
    for (int k=0;k<ND;k++){
        float yk = yr[k];
        ss_y += yk*yk;
        const float* wr = w11_1 + k*NH2;
        #pragma unroll
        for (int j=0;j<NH2;j++) h[j] += yk*wr[j];
    }
    #pragma unroll
    for (int j=0;j<NH2;j++) h[j] = fmaxf(h[j],0.f);
    #pragma unroll
    for (int j=0;j<NH2;j++) o[j] = b11_2[j];
    #pragma unroll
    for (int k=0;k<NH2;k++){
        float hk = h[k];
        const float* wr = w11_2 + k*NH2;
        #pragma unroll
        for (int j=0;j<NH2;j++) o[j] += hk*wr[j];
    }
    #pragma unroll
    for (int j=0;j<NH2;j++){ oyp[j]=o[j]; ss_oy += o[j]*o[j]; }

    // ---- out_c chain: cc=[ox,oy] -> relu(@w12_1+b) -> relu(@w12_2+b) ----
    float ox[NH2];
    #pragma unroll
    for (int j=0;j<NH2;j++) ox[j] = oxp[j];   // reload ox (L1-hot)

    float o3[NH2];
    #pragma unroll
    for (int d=0;d<NH2;d++) o3[d] = b12_2[d];
    for (int j=0;j<NH;j++){
        float s = b12_1[j];
        const float* w1c = w12_1 + j;         // column j, stride NH
        #pragma unroll
        for (int k=0;k<NH2;k++) s += ox[k]*w1c[k*NH];
        #pragma unroll
        for (int k=0;k<NH2;k++) s += o[k]*w1c[(NH2+k)*NH];
        s = fmaxf(s,0.f);
        const float* w2r = w12_2 + j*NH2;
        #pragma unroll
        for (int d=0;d<NH2;d++) o3[d] += s*w2r[d];
    }
    #pragma unroll
    for (int d=0;d<NH2;d++) o3[d] = fmaxf(o3[d],0.f);

    // ---- block reductions ----
    float r0=ss_x, r1=ss_y, r2=ss_ox, r3=ss_oy;
    #pragma unroll
    for (int off=32; off; off>>=1){
        r0 += __shfl_down(r0,off); r1 += __shfl_down(r1,off);
        r2 += __shfl_down(r2,off); r3 += __shfl_down(r3,off);
    }
    if (lane==0){ s_sc[wv][0]=r0; s_sc[wv][1]=r1; s_sc[wv][2]=r2; s_sc[wv][3]=r3; }

    #pragma unroll
    for (int d=0; d<NH2; d++){
        float vv = o3[d];
        #pragma unroll
        for (int off=32; off; off>>=1) vv += __shfl_down(vv,off);
        if (lane==0) s_part[wv][d] = vv;
    }
    __syncthreads();

    if (n==0){
        #pragma unroll
        for (int q=0;q<4;q++){
            float s = s_sc[0][q]+s_sc[1][q]+s_sc[2][q]+s_sc[3][q];
            norms[b*4+q] = sqrtf(s);
        }
    }
    if (n < NH2){
        s_mean[n] = (s_part[0][n]+s_part[1][n]+s_part[2][n]+s_part[3][n]) * (1.0f/NS);
    }
    __syncthreads();
    if (n < 3){
        float s = bc1[n];
        for (int d=0; d<NH2; d++) s += s_mean[d]*wc1[d*3+n];
        s_outc[n] = s;
        dout[b*3+n] = s;
    }
    __syncthreads();
    if (n==0){
        float a0=s_outc[0], a1=s_outc[1], a2=s_outc[2];
        float m = fmaxf(a0,fmaxf(a1,a2));
        float e0=expf(a0-m), e1=expf(a1-m), e2=expf(a2-m);
        float inv = 1.f/(e0+e1+e2);
        dout[640 + b*3+0]=e0*inv;
        dout[640 + b*3+1]=e1*inv;
        dout[640 + b*3+2]=e2*inv;
    }
}

// ---------------- K2: ridge regression (one block per (batch, side)) ----------------
// side 0: Z=out_xn, T=yy -> resx, rx ; side 1: Z=out_yn, T=xx -> resy, ry
__global__ __launch_bounds__(256) void k2_reg(
    const float* __restrict__ feat_x, const float* __restrict__ feat_y,
    const float* __restrict__ x, const float* __restrict__ y,
    const float* __restrict__ norms,
    float* __restrict__ resx, float* __restrict__ resy,
    float* __restrict__ dout)
{
    const int b = blockIdx.x >> 1, side = blockIdx.x & 1;
    const float* feat = side ? feat_y : feat_x;
    const float* targ = side ? x : y;
    const float zinv = 1.f / norms[b*4 + 2 + side];
    const float tinv = 1.f / norms[b*4 + (side ? 0 : 1)];
    float* res = side ? resy : resx;
    float* lout = dout + (side ? 256 : 192);
    const int t = threadIdx.x;

    __shared__ float A[65][65];
    __shared__ float R[65][64];
    __shared__ float Zt[32][65];
    __shared__ float Tt[32][64];
    __shared__ float s_l[4];

    for (int i=t; i<65*65; i+=256) (&A[0][0])[i] = 0.f;
    for (int i=t; i<65*64; i+=256) (&R[0][0])[i] = 0.f;
    __syncthreads();

    for (int tile=0; tile<8; tile++){
        for (int i=t; i<32*65; i+=256){
            int r=i/65, c=i%65;
            Zt[r][c] = (c==0) ? 1.f : feat[((size_t)b*NS + tile*32 + r)*NH2 + (c-1)]*zinv;
        }
        for (int i=t; i<32*64; i+=256){
            int r=i>>6, c=i&63;
            Tt[r][c] = targ[((size_t)b*NS + tile*32 + r)*ND + c]*tinv;
        }
        __syncthreads();
        for (int e=t; e<65*65; e+=256){
            int i=e/65, j=e%65;
            float s=0.f;
            for (int r=0;r<32;r++) s += Zt[r][i]*Zt[r][j];
            (&A[0][0])[e] += s;
        }
        for (int e=t; e<65*64; e+=256){
            int i=e>>6, j=e&63;
            float s=0.f;
            for (int r=0;r<32;r++) s += Zt[r][i]*Tt[r][j];
            (&R[0][0])[e] += s;
        }
        __syncthreads();
    }
    if (t>=1 && t<65) A[t][t] += 1.0f;   // REG=1, ridge[0,0]=0
    __syncthreads();

    // forward elimination (SPD, no pivoting needed)
    for (int k=0; k<64; k++){
        int nrows = 64 - k;
        if (t < nrows){
            int i = k+1+t;
            float f = A[i][k]/A[k][k];
            for (int j=k; j<65; j++) A[i][j] -= f*A[k][j];
            for (int d=0; d<64; d++) R[i][d] -= f*R[k][d];
        }
        __syncthreads();
    }
    // back substitution, in place in R; thread t owns column t
    if (t < 64){
        for (int k=64; k>=0; k--){
            float w = R[k][t];
            for (int j=k+1; j<65; j++) w -= A[k][j]*R[j][t];
            R[k][t] = w / A[k][k];
        }
    }
    __syncthreads();

    // residual: thread n = row n ; res = T - X W ; loss = sum(res^2)
    {
        const int n = t;
        const float* fr = feat + ((size_t)b*NS + n)*NH2;
        const float* tr = targ + ((size_t)b*NS + n)*ND;
        float z[NH2];
        #pragma unroll
        for (int j=0;j<NH2;j++) z[j] = fr[j]*zinv;
        float ll = 0.f;
        float* rp = res + ((size_t)b*NS + n)*ND;
        for (int d=0; d<ND; d++){
            float p = R[0][d];
            #pragma unroll
            for (int j=0;j<NH2;j++) p += z[j]*R[j+1][d];
            float rr = tr[d]*tinv - p;
            rp[d] = rr;
            ll += rr*rr;
        }
        #pragma unroll
        for (int off=32; off; off>>=1) ll += __shfl_down(ll,off);
        if ((t&63)==0) s_l[t>>6] = ll;
        __syncthreads();
        if (t==0) lout[b] = s_l[0]+s_l[1]+s_l[2]+s_l[3];
    }
}

// ---------------- K3: Renyi-2 MI via Frobenius sums (no eig) ----------------
// side 0: mi(resx, x) -> ex ; side 1: mi(resy, y) -> ey
__global__ __launch_bounds__(256) void k3_renyi(
    const float* __restrict__ resx, const float* __restrict__ resy,
    const float* __restrict__ x, const float* __restrict__ y,
    float* __restrict__ dout)
{
    const int b = blockIdx.x >> 1, side = blockIdx.x & 1;
    const float* Ap = side ? resy : resx;
    const float* Bp = side ? y : x;
    const int i = threadIdx.x;

    __shared__ float At[64][64];
    __shared__ float Bt[64][64];
    __shared__ float anL[NS], bnL[NS];
    __shared__ float red[4][3];

    float av[ND], bv[ND];
    const float* ap = Ap + ((size_t)b*NS + i)*ND;
    const float* bp = Bp + ((size_t)b*NS + i)*ND;
    float an=0.f, bn=0.f;
    #pragma unroll
    for (int k=0;k<ND;k++){
        av[k]=ap[k]; an += av[k]*av[k];
        bv[k]=bp[k]; bn += bv[k]*bv[k];
    }
    anL[i]=an; bnL[i]=bn;
    __syncthreads();

    float Sa=0.f, Sb=0.f, Sab=0.f;
    for (int tile=0; tile<4; tile++){
        const float* asrc = Ap + ((size_t)b*NS + tile*64)*ND;
        const float* bsrc = Bp + ((size_t)b*NS + tile*64)*ND;
        int base = i*16;
        #pragma unroll
        for (int c=0;c<16;c++){
            (&At[0][0])[base+c] = asrc[base+c];
            (&Bt[0][0])[base+c] = bsrc[base+c];
        }
        __syncthreads();
        for (int j=0;j<64;j++){
            float da=0.f, db=0.f;
            #pragma unroll
            for (int k=0;k<ND;k++){ da += av[k]*At[j][k]; db += bv[k]*Bt[j][k]; }
            float dda = an + anL[tile*64+j] - 2.f*da;
            float ddb = bn + bnL[tile*64+j] - 2.f*db;
            float ka = expf(-dda), kb = expf(-ddb);
            Sa += ka*ka; Sb += kb*kb;
            float kk = ka*kb; Sab += kk*kk;
        }
        __syncthreads();
    }
    #pragma unroll
    for (int off=32; off; off>>=1){
        Sa += __shfl_down(Sa,off); Sb += __shfl_down(Sb,off); Sab += __shfl_down(Sab,off);
    }
    if ((i&63)==0){ red[i>>6][0]=Sa; red[i>>6][1]=Sb; red[i>>6][2]=Sab; }
    __syncthreads();
    if (i==0){
        float sa = red[0][0]+red[1][0]+red[2][0]+red[3][0];
        float sb = red[0][1]+red[1][1]+red[2][1]+red[3][1];
        float sab= red[0][2]+red[1][2]+red[2][2]+red[3][2];
        // H = -log2(S / N^2) = 16 - log2(S), N=256
        float Hx = 16.f - log2f(sa);
        float Hy = 16.f - log2f(sb);
        float Hxy= 16.f - log2f(sab);
        float mi = (Hx + Hy - Hxy) / fmaxf(Hx, Hy);
        dout[(side ? 384 : 320) + b] = mi;
    }
}

// ---------------- K4: batchnorm + final MLP + prob2 ----------------
__global__ __launch_bounds__(64) void k4_final(
    const float* __restrict__ bn_gamma, const float* __restrict__ bn_beta,
    const float* __restrict__ w2, const float* __restrict__ b2,
    const float* __restrict__ wc2, const float* __restrict__ bc2,
    float* __restrict__ dout)
{
    const int t = threadIdx.x; // batch index 0..63
    __shared__ float ic[64][5];
    __shared__ float mu[5], iv[5];
    ic[t][0]=dout[t*3+0]; ic[t][1]=dout[t*3+1]; ic[t][2]=dout[t*3+2];
    ic[t][3]=dout[320+t]; ic[t][4]=dout[384+t];
    __syncthreads();
    if (t<5){
        float m=0.f;
        for (int b=0;b<64;b++) m += ic[b][t];
        m *= (1.f/64);
        float v=0.f;
        for (int b=0;b<64;b++){ float d=ic[b][t]-m; v += d*d; }
        v *= (1.f/64);
        mu[t]=m; iv[t]=1.f/sqrtf(v+1e-5f);
    }
    __syncthreads();
    float vn[5];
    #pragma unroll
    for (int c=0;c<5;c++) vn[c] = (ic[t][c]-mu[c])*iv[c]*bn_gamma[c]+bn_beta[c];
    float o0=bc2[0], o1=bc2[1], o2=bc2[2];
    for (int j=0;j<64;j++){
        float h = b2[j];
        #pragma unroll
        for (int c=0;c<5;c++) h += vn[c]*w2[c*64+j];
        h = fmaxf(h,0.f);
        o0 += h*wc2[j*3+0]; o1 += h*wc2[j*3+1]; o2 += h*wc2[j*3+2];
    }
    dout[448+t*3+0]=o0; dout[448+t*3+1]=o1; dout[448+t*3+2]=o2;
    float m = fmaxf(o0,fmaxf(o1,o2));
    float e0=expf(o0-m), e1=expf(o1-m), e2=expf(o2-m);
    float inv=1.f/(e0+e1+e2);
    dout[832+t*3+0]=e0*inv; dout[832+t*3+1]=e1*inv; dout[832+t*3+2]=e2*inv;
}

extern "C" void kernel_launch(void* const* d_in, const int* in_sizes, int n_in,
                              void* d_out, int out_size, void* d_ws, size_t ws_size,
                              hipStream_t stream)
{
    const float* x     = (const float*)d_in[0];
    const float* y     = (const float*)d_in[1];
    const float* w11_1 = (const float*)d_in[2];
    const float* b11_1 = (const float*)d_in[3];
    const float* w11_2 = (const float*)d_in[4];
    const float* b11_2 = (const float*)d_in[5];
    const float* w12_1 = (const float*)d_in[6];
    const float* b12_1 = (const float*)d_in[7];
    const float* w12_2 = (const float*)d_in[8];
    const float* b12_2 = (const float*)d_in[9];
    const float* wc1   = (const float*)d_in[10];
    const float* bc1   = (const float*)d_in[11];
    const float* bn_g  = (const float*)d_in[12];
    const float* bn_b  = (const float*)d_in[13];
    const float* w2    = (const float*)d_in[14];
    const float* b2    = (const float*)d_in[15];
    const float* wc2   = (const float*)d_in[16];
    const float* bc2   = (const float*)d_in[17];

    float* dout = (float*)d_out;
    float* ws   = (float*)d_ws;
    float* out_x = ws;                      // 64*256*64 = 1,048,576 floats
    float* out_y = ws + (1u<<20);
    float* resx  = ws + (2u<<20);
    float* resy  = ws + (3u<<20);
    float* norms = ws + (4u<<20);           // 256 floats

    hipLaunchKernelGGL(k1_mlp, dim3(NB), dim3(256), 0, stream,
        x,y,w11_1,b11_1,w11_2,b11_2,w12_1,b12_1,w12_2,b12_2,wc1,bc1,
        out_x,out_y,norms,dout);
    hipLaunchKernelGGL(k2_reg, dim3(2*NB), dim3(256), 0, stream,
        out_x,out_y,x,y,norms,resx,resy,dout);
    hipLaunchKernelGGL(k3_renyi, dim3(2*NB), dim3(256), 0, stream,
        resx,resy,x,y,dout);
    hipLaunchKernelGGL(k4_final, dim3(1), dim3(64), 0, stream,
        bn_g,bn_b,w2,b2,wc2,bc2,dout);
}

// Round 2
// 181.035 us; speedup vs baseline: 6.7074x; 6.7074x over previous
//
#include <hip/hip_runtime.h>
#include <math.h>

#define NB 64
#define NS 256
#define ND 64
#define NH2 64
#define NH 128

// d_out layout (floats):
// 0: out_c[64*3]; 192: rx[64]; 256: ry[64]; 320: ex[64]; 384: ey[64];
// 448: out_c_f[64*3]; 640: prob1[64*3]; 832: prob2[64*3]   (total 1024)

#define FMA8(A_, a_, w0_, w1_) \
    A_[0]+=a_*w0_.x; A_[1]+=a_*w0_.y; A_[2]+=a_*w0_.z; A_[3]+=a_*w0_.w; \
    A_[4]+=a_*w1_.x; A_[5]+=a_*w1_.y; A_[6]+=a_*w1_.z; A_[7]+=a_*w1_.w;

// =================== K1: fused mlp11(x,y) + out_c chain partial means ===================
__global__ __launch_bounds__(256) void k1_fused(
    const float* __restrict__ x, const float* __restrict__ y,
    const float* __restrict__ w11_1, const float* __restrict__ b11_1,
    const float* __restrict__ w11_2, const float* __restrict__ b11_2,
    const float* __restrict__ w12_1, const float* __restrict__ b12_1,
    const float* __restrict__ w12_2, const float* __restrict__ b12_2,
    float* __restrict__ out_x, float* __restrict__ out_y,
    float* __restrict__ mean_part)
{
    const int b = blockIdx.x >> 2, tile = blockIdx.x & 3;
    const int t = threadIdx.x;
    const int row0 = b*NS + tile*64;

    __shared__ float sW1[64*64];
    __shared__ float sW2[64*64];
    __shared__ float sX [64*68];
    __shared__ float sH [64*68];
    __shared__ float sIN[64*132];
    __shared__ float sH2[64*132];

    // stage mlp11 weights (4096 floats each)
    {
        const float4* g1 = (const float4*)w11_1;
        const float4* g2 = (const float4*)w11_2;
        float4* d1 = (float4*)sW1;
        float4* d2 = (float4*)sW2;
        #pragma unroll
        for (int u=0;u<4;u++){ d1[t*4+u] = g1[t*4+u]; d2[t*4+u] = g2[t*4+u]; }
    }

    const int p   = t>>3;          // 0..31 row-pair
    const int c8  = (t&7)*8;       // 8-col group (phase A, GEMM2)
    const int p4  = t>>4;          // 0..15 (GEMM1 rows p4+16u)
    const int c8b = (t&15)*8;      // GEMM1 8-col group (128 wide)

    for (int s=0; s<2; s++){
        const float* src = s ? y : x;
        float* dstG = s ? out_y : out_x;
        // stage 64x64 input tile
        {
            int r = t>>2, c = (t&3)*16;
            const float4* g = (const float4*)(src + ((size_t)(row0 + r))*ND + c);
            float4* d = (float4*)(sX + r*68 + c);
            #pragma unroll
            for (int u=0;u<4;u++) d[u] = g[u];
        }
        __syncthreads();
        // H = relu(X @ W1 + b1)
        {
            float acc0[8], acc1[8];
            #pragma unroll
            for (int u=0;u<8;u++){ float bb = b11_1[c8+u]; acc0[u]=bb; acc1[u]=bb; }
            for (int k=0;k<64;k++){
                float a0 = sX[(2*p  )*68 + k];
                float a1 = sX[(2*p+1)*68 + k];
                const float4* w = (const float4*)(sW1 + k*64 + c8);
                float4 w0 = w[0], w1 = w[1];
                FMA8(acc0, a0, w0, w1);
                FMA8(acc1, a1, w0, w1);
            }
            float4* d0 = (float4*)(sH + (2*p  )*68 + c8);
            float4* d1 = (float4*)(sH + (2*p+1)*68 + c8);
            d0[0] = make_float4(fmaxf(acc0[0],0.f),fmaxf(acc0[1],0.f),fmaxf(acc0[2],0.f),fmaxf(acc0[3],0.f));
            d0[1] = make_float4(fmaxf(acc0[4],0.f),fmaxf(acc0[5],0.f),fmaxf(acc0[6],0.f),fmaxf(acc0[7],0.f));
            d1[0] = make_float4(fmaxf(acc1[0],0.f),fmaxf(acc1[1],0.f),fmaxf(acc1[2],0.f),fmaxf(acc1[3],0.f));
            d1[1] = make_float4(fmaxf(acc1[4],0.f),fmaxf(acc1[5],0.f),fmaxf(acc1[6],0.f),fmaxf(acc1[7],0.f));
        }
        __syncthreads();
        // O = H @ W2 + b2  (no relu) -> global + sIN
        {
            float acc0[8], acc1[8];
            #pragma unroll
            for (int u=0;u<8;u++){ float bb = b11_2[c8+u]; acc0[u]=bb; acc1[u]=bb; }
            for (int k=0;k<64;k++){
                float a0 = sH[(2*p  )*68 + k];
                float a1 = sH[(2*p+1)*68 + k];
                const float4* w = (const float4*)(sW2 + k*64 + c8);
                float4 w0 = w[0], w1 = w[1];
                FMA8(acc0, a0, w0, w1);
                FMA8(acc1, a1, w0, w1);
            }
            float4 v00 = make_float4(acc0[0],acc0[1],acc0[2],acc0[3]);
            float4 v01 = make_float4(acc0[4],acc0[5],acc0[6],acc0[7]);
            float4 v10 = make_float4(acc1[0],acc1[1],acc1[2],acc1[3]);
            float4 v11 = make_float4(acc1[4],acc1[5],acc1[6],acc1[7]);
            *(float4*)(dstG + ((size_t)(row0+2*p  ))*NH2 + c8    ) = v00;
            *(float4*)(dstG + ((size_t)(row0+2*p  ))*NH2 + c8 + 4) = v01;
            *(float4*)(dstG + ((size_t)(row0+2*p+1))*NH2 + c8    ) = v10;
            *(float4*)(dstG + ((size_t)(row0+2*p+1))*NH2 + c8 + 4) = v11;
            *(float4*)(sIN + (2*p  )*132 + s*64 + c8    ) = v00;
            *(float4*)(sIN + (2*p  )*132 + s*64 + c8 + 4) = v01;
            *(float4*)(sIN + (2*p+1)*132 + s*64 + c8    ) = v10;
            *(float4*)(sIN + (2*p+1)*132 + s*64 + c8 + 4) = v11;
        }
        __syncthreads();
    }

    // GEMM1: H1[64][128] = relu(sIN @ w12_1 + b12_1)
    {
        float acc[4][8];
        #pragma unroll
        for (int v=0;v<8;v++){
            float bb = b12_1[c8b+v];
            acc[0][v]=bb; acc[1][v]=bb; acc[2][v]=bb; acc[3][v]=bb;
        }
        for (int kk=0;kk<4;kk++){
            __syncthreads();
            {
                const float4* g = (const float4*)(w12_1 + kk*32*NH);
                float4* d = (float4*)sW1;
                #pragma unroll
                for (int u=0;u<4;u++) d[t*4+u] = g[t*4+u];
            }
            __syncthreads();
            for (int k=0;k<32;k++){
                float a0 = sIN[(p4    )*132 + kk*32+k];
                float a1 = sIN[(p4+16 )*132 + kk*32+k];
                float a2 = sIN[(p4+32 )*132 + kk*32+k];
                float a3 = sIN[(p4+48 )*132 + kk*32+k];
                const float4* w = (const float4*)(sW1 + k*NH + c8b);
                float4 w0 = w[0], w1 = w[1];
                FMA8(acc[0], a0, w0, w1);
                FMA8(acc[1], a1, w0, w1);
                FMA8(acc[2], a2, w0, w1);
                FMA8(acc[3], a3, w0, w1);
            }
        }
        #pragma unroll
        for (int u=0;u<4;u++){
            float4 h0 = make_float4(fmaxf(acc[u][0],0.f),fmaxf(acc[u][1],0.f),fmaxf(acc[u][2],0.f),fmaxf(acc[u][3],0.f));
            float4 h1 = make_float4(fmaxf(acc[u][4],0.f),fmaxf(acc[u][5],0.f),fmaxf(acc[u][6],0.f),fmaxf(acc[u][7],0.f));
            *(float4*)(sH2 + (p4+16*u)*132 + c8b    ) = h0;
            *(float4*)(sH2 + (p4+16*u)*132 + c8b + 4) = h1;
        }
    }
    __syncthreads();
    // GEMM2: OUT2[64][64] = relu(sH2 @ w12_2 + b12_2) -> sX scratch
    {
        float acc0[8], acc1[8];
        #pragma unroll
        for (int u=0;u<8;u++){ float bb = b12_2[c8+u]; acc0[u]=bb; acc1[u]=bb; }
        for (int kk=0;kk<2;kk++){
            __syncthreads();
            {
                const float4* g = (const float4*)(w12_2 + kk*64*NH2);
                float4* d = (float4*)sW1;
                #pragma unroll
                for (int u=0;u<4;u++) d[t*4+u] = g[t*4+u];
            }
            __syncthreads();
            for (int k=0;k<64;k++){
                float a0 = sH2[(2*p  )*132 + kk*64+k];
                float a1 = sH2[(2*p+1)*132 + kk*64+k];
                const float4* w = (const float4*)(sW1 + k*64 + c8);
                float4 w0 = w[0], w1 = w[1];
                FMA8(acc0, a0, w0, w1);
                FMA8(acc1, a1, w0, w1);
            }
        }
        float4* d0 = (float4*)(sX + (2*p  )*68 + c8);
        float4* d1 = (float4*)(sX + (2*p+1)*68 + c8);
        d0[0] = make_float4(fmaxf(acc0[0],0.f),fmaxf(acc0[1],0.f),fmaxf(acc0[2],0.f),fmaxf(acc0[3],0.f));
        d0[1] = make_float4(fmaxf(acc0[4],0.f),fmaxf(acc0[5],0.f),fmaxf(acc0[6],0.f),fmaxf(acc0[7],0.f));
        d1[0] = make_float4(fmaxf(acc1[0],0.f),fmaxf(acc1[1],0.f),fmaxf(acc1[2],0.f),fmaxf(acc1[3],0.f));
        d1[1] = make_float4(fmaxf(acc1[4],0.f),fmaxf(acc1[5],0.f),fmaxf(acc1[6],0.f),fmaxf(acc1[7],0.f));
    }
    __syncthreads();
    if (t < 64){
        float ssum = 0.f;
        for (int r=0;r<64;r++) ssum += sX[r*68 + t];
        mean_part[((size_t)(b*4 + tile))*64 + t] = ssum;
    }
}

// =================== K2: ridge regression, self-normalizing ===================
__global__ __launch_bounds__(256) void k2_reg(
    const float* __restrict__ feat_x, const float* __restrict__ feat_y,
    const float* __restrict__ x, const float* __restrict__ y,
    float* __restrict__ resx, float* __restrict__ resy,
    float* __restrict__ resn, float* __restrict__ rawn,
    float* __restrict__ dout)
{
    const int b = blockIdx.x >> 1, side = blockIdx.x & 1;
    const float* feat = side ? feat_y : feat_x;
    const float* targ = side ? x : y;
    float* res = side ? resy : resx;
    const int t = threadIdx.x;
    const int lane = t & 63, wv = t >> 6;

    __shared__ float A[65*68];
    __shared__ float R[65*68];
    __shared__ float Zt[64*68];
    __shared__ float Tt[64*68];
    __shared__ float fcol[72];
    __shared__ float csp[4*68];
    __shared__ float sc[16];

    const int p = t>>3, c8 = (t&7)*8;
    float Aacc[2][8], Racc[2][8];
    #pragma unroll
    for (int u=0;u<2;u++)
        #pragma unroll
        for (int v=0;v<8;v++){ Aacc[u][v]=0.f; Racc[u][v]=0.f; }
    float cz=0.f, ct=0.f, tsq=0.f;
    const int cc = t&63, rq = t>>6;

    // ---- build raw gram A'=Z^T Z (64x64), R'=Z^T T, col sums, sum T^2 ----
    for (int tl=0; tl<4; tl++){
        if (tl) __syncthreads();
        {
            int r = t>>2, c = (t&3)*16;
            const float4* gz = (const float4*)(feat + ((size_t)(b*NS + tl*64 + r))*NH2 + c);
            const float4* gt = (const float4*)(targ + ((size_t)(b*NS + tl*64 + r))*ND + c);
            float4* dz = (float4*)(Zt + r*68 + c);
            float4* dt = (float4*)(Tt + r*68 + c);
            #pragma unroll
            for (int u=0;u<4;u++){ dz[u]=gz[u]; dt[u]=gt[u]; }
        }
        __syncthreads();
        for (int r=0;r<64;r++){
            float a0 = Zt[r*68 + 2*p];
            float a1 = Zt[r*68 + 2*p+1];
            const float4* zj = (const float4*)(Zt + r*68 + c8);
            float4 z0 = zj[0], z1 = zj[1];
            const float4* tj = (const float4*)(Tt + r*68 + c8);
            float4 q0 = tj[0], q1 = tj[1];
            FMA8(Aacc[0], a0, z0, z1);
            FMA8(Aacc[1], a1, z0, z1);
            FMA8(Racc[0], a0, q0, q1);
            FMA8(Racc[1], a1, q0, q1);
        }
        #pragma unroll
        for (int rr=0; rr<16; rr++){
            int r = rq*16 + rr;
            cz += Zt[r*68 + cc];
            float tv = Tt[r*68 + cc];
            ct += tv; tsq += tv*tv;
        }
    }
    __syncthreads();
    #pragma unroll
    for (int u=0;u<2;u++)
        #pragma unroll
        for (int v=0;v<8;v++){
            A[(1+2*p+u)*68 + 1+c8+v] = Aacc[u][v];
            R[(1+2*p+u)*68 + c8+v]   = Racc[u][v];
        }
    csp[rq*68+cc] = cz;
    __syncthreads();
    if (t<64){
        float s = csp[0*68+t]+csp[1*68+t]+csp[2*68+t]+csp[3*68+t];
        A[0*68 + 1+t] = s;
        A[(1+t)*68 + 0] = s;
    }
    __syncthreads();
    csp[rq*68+cc] = ct;
    __syncthreads();
    if (t<64){
        float s = csp[0*68+t]+csp[1*68+t]+csp[2*68+t]+csp[3*68+t];
        R[0*68 + t] = s;
    }
    if (t==0) A[0] = 256.0f;
    {
        float tq = tsq;
        #pragma unroll
        for (int off=32; off; off>>=1) tq += __shfl_down(tq, off);
        if (lane==0) sc[8+wv] = tq;
    }
    __syncthreads();
    if (t<64){
        float dg = A[(1+t)*68 + (1+t)];
        #pragma unroll
        for (int off=32; off; off>>=1) dg += __shfl_down(dg, off);
        if (t==0){
            float zn2 = dg;
            float tn2 = sc[8]+sc[9]+sc[10]+sc[11];
            sc[0] = 1.0f/sqrtf(zn2);
            sc[1] = 1.0f/sqrtf(tn2);
        }
    }
    __syncthreads();
    const float zinv = sc[0], tinv = sc[1];
    // scale in place + ridge
    {
        const int qd = t&3;
        for (int i0 = t>>2; i0 < 65; i0 += 64){
            for (int j = qd; j < 65; j += 4){
                float f;
                if (i0==0 && j==0) f = 1.0f;
                else if (i0==0 || j==0) f = zinv;
                else f = zinv*zinv;
                float v = A[i0*68+j]*f;
                if (i0==j && i0>=1) v += 1.0f;   // REG = 1
                A[i0*68+j] = v;
            }
            float rf = (i0==0) ? tinv : (zinv*tinv);
            for (int d = qd; d < 64; d += 4)
                R[i0*68+d] *= rf;
        }
    }
    // ---- backward Gauss-Jordan, distributed ----
    for (int k=64; k>=0; k--){
        __syncthreads();
        if (t < 65) fcol[t] = A[t*68 + k];
        if (t == 0) sc[2] = 1.0f / A[k*68 + k];
        __syncthreads();
        int i = t>>2; i += (i >= k);
        const float fi = fcol[i] * sc[2];
        const int qd = t&3;
        const int nq = k >> 2;
        for (int q = qd; q < nq; q += 4){
            float4 pk = *(const float4*)(A + k*68 + 4*q);
            float4 pi = *(float4*)(A + i*68 + 4*q);
            pi.x -= fi*pk.x; pi.y -= fi*pk.y; pi.z -= fi*pk.z; pi.w -= fi*pk.w;
            *(float4*)(A + i*68 + 4*q) = pi;
        }
        {
            int jt = 4*nq + qd;
            if (jt < k) A[i*68+jt] -= fi * A[k*68+jt];
        }
        #pragma unroll
        for (int q0 = 0; q0 < 4; q0++){
            int q = qd + q0*4;
            float4 rk = *(const float4*)(R + k*68 + 4*q);
            float4 ri = *(float4*)(R + i*68 + 4*q);
            ri.x -= fi*rk.x; ri.y -= fi*rk.y; ri.z -= fi*rk.z; ri.w -= fi*rk.w;
            *(float4*)(R + i*68 + 4*q) = ri;
        }
    }
    __syncthreads();
    // W = R / diag(A)
    {
        const int qd = t&3;
        for (int i0 = t>>2; i0 < 65; i0 += 64){
            float dinv = 1.0f / A[i0*68+i0];
            for (int q = qd; q < 16; q += 4){
                float4 r4 = *(float4*)(R + i0*68 + 4*q);
                r4.x*=dinv; r4.y*=dinv; r4.z*=dinv; r4.w*=dinv;
                *(float4*)(R + i0*68 + 4*q) = r4;
            }
        }
    }
    if (t==0) sc[3] = 0.0f;
    // ---- residual passes (4 x 64 rows) ----
    float* rnp = Tt;
    float* rqp = Tt + 64*9;
    for (int pass=0; pass<4; pass++){
        __syncthreads();
        {
            int r = t>>2, c = (t&3)*16;
            const float4* gz = (const float4*)(feat + ((size_t)(b*NS + pass*64 + r))*NH2 + c);
            float4* dz = (float4*)(Zt + r*68 + c);
            #pragma unroll
            for (int u=0;u<4;u++){
                float4 v = gz[u];
                v.x*=zinv; v.y*=zinv; v.z*=zinv; v.w*=zinv;
                dz[u]=v;
            }
        }
        __syncthreads();
        float acc0[8], acc1[8];
        {
            const float4* w = (const float4*)(R + 0*68 + c8);
            float4 w0 = w[0], w1 = w[1];
            acc0[0]=w0.x; acc0[1]=w0.y; acc0[2]=w0.z; acc0[3]=w0.w;
            acc0[4]=w1.x; acc0[5]=w1.y; acc0[6]=w1.z; acc0[7]=w1.w;
            #pragma unroll
            for (int u=0;u<8;u++) acc1[u]=acc0[u];
        }
        for (int j=1;j<=64;j++){
            float a0 = Zt[(2*p  )*68 + (j-1)];
            float a1 = Zt[(2*p+1)*68 + (j-1)];
            const float4* w = (const float4*)(R + j*68 + c8);
            float4 w0=w[0], w1=w[1];
            FMA8(acc0, a0, w0, w1);
            FMA8(acc1, a1, w0, w1);
        }
        #pragma unroll
        for (int u=0;u<2;u++){
            float* accp = u ? acc1 : acc0;
            int gr = b*NS + pass*64 + 2*p + u;
            const float4* tg = (const float4*)(targ + (size_t)gr*ND + c8);
            float4 q0 = tg[0], q1 = tg[1];
            float rv0 = q0.x*tinv - accp[0];
            float rv1 = q0.y*tinv - accp[1];
            float rv2 = q0.z*tinv - accp[2];
            float rv3 = q0.w*tinv - accp[3];
            float rv4 = q1.x*tinv - accp[4];
            float rv5 = q1.y*tinv - accp[5];
            float rv6 = q1.z*tinv - accp[6];
            float rv7 = q1.w*tinv - accp[7];
            float rn_ = rv0*rv0+rv1*rv1+rv2*rv2+rv3*rv3+rv4*rv4+rv5*rv5+rv6*rv6+rv7*rv7;
            float rq_ = q0.x*q0.x+q0.y*q0.y+q0.z*q0.z+q0.w*q0.w
                      + q1.x*q1.x+q1.y*q1.y+q1.z*q1.z+q1.w*q1.w;
            *(float4*)(res + (size_t)gr*ND + c8    ) = make_float4(rv0,rv1,rv2,rv3);
            *(float4*)(res + (size_t)gr*ND + c8 + 4) = make_float4(rv4,rv5,rv6,rv7);
            rnp[(2*p+u)*9 + (t&7)] = rn_;
            rqp[(2*p+u)*9 + (t&7)] = rq_;
        }
        __syncthreads();
        if (t < 64){
            float rn_=0.f, rq_=0.f;
            #pragma unroll
            for (int g=0; g<8; g++){ rn_ += rnp[t*9+g]; rq_ += rqp[t*9+g]; }
            resn[((size_t)(side*NB + b))*NS + pass*64 + t] = rn_;
            rawn[((size_t)(side*NB + b))*NS + pass*64 + t] = rq_;
            float l = rn_;
            #pragma unroll
            for (int off=32; off; off>>=1) l += __shfl_down(l, off);
            if (t==0) sc[3] += l;
        }
    }
    __syncthreads();
    if (t==0) dout[(side?256:192) + b] = sc[3];
}

// =================== K3: Renyi-2 via Gram Frobenius sums ===================
__global__ __launch_bounds__(256) void k3_renyi(
    const float* __restrict__ resx, const float* __restrict__ resy,
    const float* __restrict__ x, const float* __restrict__ y,
    const float* __restrict__ resn, const float* __restrict__ rawn,
    float* __restrict__ part3)
{
    const int blk = blockIdx.x;
    const int b = blk >> 2, side = (blk >> 1) & 1, h = blk & 1;
    const float* Am = side ? resy : resx;
    const float* Bm = side ? y : x;
    const float* nA = resn + ((size_t)(side*NB + b))*NS;
    const float* nBr = rawn + ((size_t)((1-side)*NB + b))*NS;  // raw norms of Bm
    const int t = threadIdx.x;
    const int lane = t&63, wv = t>>6;

    __shared__ float AI[128*68];
    __shared__ float BI[128*68];
    __shared__ float AJ[64*68];
    __shared__ float BJ[64*68];
    __shared__ float nAI[128], nBI[128];
    __shared__ float nAJ[64], nBJ[64];
    __shared__ float red[12];

    {
        int r = t>>1, c = (t&1)*32;
        const float4* ga = (const float4*)(Am + ((size_t)(b*NS + h*128 + r))*ND + c);
        const float4* gb = (const float4*)(Bm + ((size_t)(b*NS + h*128 + r))*ND + c);
        float4* da = (float4*)(AI + r*68 + c);
        float4* db = (float4*)(BI + r*68 + c);
        #pragma unroll
        for (int u=0;u<8;u++){ da[u]=ga[u]; db[u]=gb[u]; }
    }
    if (t < 128){ nAI[t] = nA[h*128 + t]; nBI[t] = nBr[h*128 + t]; }

    const int iq = t>>3;        // rows iq, iq+32, iq+64, iq+96
    const int j8 = (t&7)*8;

    float Sa=0.f, Sb=0.f, Sab=0.f;

    for (int jt=0; jt<4; jt++){
        __syncthreads();
        {
            int j = t>>2, k0 = (t&3)*16;
            const float4* ga = (const float4*)(Am + ((size_t)(b*NS + jt*64 + j))*ND + k0);
            const float4* gb = (const float4*)(Bm + ((size_t)(b*NS + jt*64 + j))*ND + k0);
            #pragma unroll
            for (int u=0;u<4;u++){
                float4 va = ga[u], vb = gb[u];
                AJ[(k0+4*u+0)*68 + j] = va.x;
                AJ[(k0+4*u+1)*68 + j] = va.y;
                AJ[(k0+4*u+2)*68 + j] = va.z;
                AJ[(k0+4*u+3)*68 + j] = va.w;
                BJ[(k0+4*u+0)*68 + j] = vb.x;
                BJ[(k0+4*u+1)*68 + j] = vb.y;
                BJ[(k0+4*u+2)*68 + j] = vb.z;
                BJ[(k0+4*u+3)*68 + j] = vb.w;
            }
        }
        if (t<64){ nAJ[t] = nA[jt*64+t]; nBJ[t] = nBr[jt*64+t]; }
        __syncthreads();
        float da[4][8], db[4][8];
        #pragma unroll
        for (int u=0;u<4;u++)
            #pragma unroll
            for (int v=0;v<8;v++){ da[u][v]=0.f; db[u][v]=0.f; }
        for (int k=0;k<64;k++){
            float a0 = AI[(iq    )*68 + k];
            float a1 = AI[(iq+32 )*68 + k];
            float a2 = AI[(iq+64 )*68 + k];
            float a3 = AI[(iq+96 )*68 + k];
            float b0 = BI[(iq    )*68 + k];
            float b1 = BI[(iq+32 )*68 + k];
            float b2 = BI[(iq+64 )*68 + k];
            float b3 = BI[(iq+96 )*68 + k];
            const float4* ja = (const float4*)(AJ + k*68 + j8);
            float4 ja0 = ja[0], ja1 = ja[1];
            const float4* jb = (const float4*)(BJ + k*68 + j8);
            float4 jb0 = jb[0], jb1 = jb[1];
            FMA8(da[0], a0, ja0, ja1);
            FMA8(da[1], a1, ja0, ja1);
            FMA8(da[2], a2, ja0, ja1);
            FMA8(da[3], a3, ja0, ja1);
            FMA8(db[0], b0, jb0, jb1);
            FMA8(db[1], b1, jb0, jb1);
            FMA8(db[2], b2, jb0, jb1);
            FMA8(db[3], b3, jb0, jb1);
        }
        #pragma unroll
        for (int u=0;u<4;u++){
            float ni_a = nAI[iq + 32*u];
            float ni_b = nBI[iq + 32*u];
            #pragma unroll
            for (int v=0; v<8; v++){
                float dda = ni_a + nAJ[j8+v] - 2.f*da[u][v];
                float ddb = ni_b + nBJ[j8+v] - 2.f*db[u][v];
                Sa  += __expf(-2.f*dda);
                Sb  += __expf(-2.f*ddb);
                Sab += __expf(-2.f*(dda+ddb));
            }
        }
    }
    #pragma unroll
    for (int off=32; off; off>>=1){
        Sa += __shfl_down(Sa,off); Sb += __shfl_down(Sb,off); Sab += __shfl_down(Sab,off);
    }
    if (lane==0){ red[wv*3+0]=Sa; red[wv*3+1]=Sb; red[wv*3+2]=Sab; }
    __syncthreads();
    if (t==0){
        float* o = part3 + ((size_t)((side*NB + b)*2 + h))*3;
        o[0] = red[0]+red[3]+red[6]+red[9];
        o[1] = red[1]+red[4]+red[7]+red[10];
        o[2] = red[2]+red[5]+red[8]+red[11];
    }
}

// =================== K4: out_c/prob1, ex/ey combine, BN + final MLP ===================
__global__ __launch_bounds__(64) void k4_final(
    const float* __restrict__ mean_part, const float* __restrict__ part3,
    const float* __restrict__ wc1, const float* __restrict__ bc1,
    const float* __restrict__ bn_gamma, const float* __restrict__ bn_beta,
    const float* __restrict__ w2, const float* __restrict__ b2,
    const float* __restrict__ wc2, const float* __restrict__ bc2,
    float* __restrict__ dout)
{
    const int t = threadIdx.x;   // batch index
    __shared__ float ic[64][5];
    __shared__ float mu[5], iv[5];

    float o0 = bc1[0], o1 = bc1[1], o2 = bc1[2];
    for (int c=0;c<64;c++){
        float mv = mean_part[(t*4+0)*64+c] + mean_part[(t*4+1)*64+c]
                 + mean_part[(t*4+2)*64+c] + mean_part[(t*4+3)*64+c];
        mv *= (1.0f/256.0f);
        o0 += mv*wc1[c*3+0]; o1 += mv*wc1[c*3+1]; o2 += mv*wc1[c*3+2];
    }
    dout[t*3+0]=o0; dout[t*3+1]=o1; dout[t*3+2]=o2;
    {
        float m = fmaxf(o0,fmaxf(o1,o2));
        float e0=__expf(o0-m), e1=__expf(o1-m), e2=__expf(o2-m);
        float inv = 1.f/(e0+e1+e2);
        dout[640+t*3+0]=e0*inv; dout[640+t*3+1]=e1*inv; dout[640+t*3+2]=e2*inv;
    }
    float exy[2];
    #pragma unroll
    for (int side=0; side<2; side++){
        const float* pp = part3 + ((size_t)((side*NB + t)*2))*3;
        float Sa = pp[0]+pp[3], Sb = pp[1]+pp[4], Sab = pp[2]+pp[5];
        float Hx  = 16.f - log2f(Sa);
        float Hy  = 16.f - log2f(Sb);
        float Hxy = 16.f - log2f(Sab);
        float mi = (Hx + Hy - Hxy) / fmaxf(Hx, Hy);
        dout[(side?384:320)+t] = mi;
        exy[side] = mi;
    }
    ic[t][0]=o0; ic[t][1]=o1; ic[t][2]=o2; ic[t][3]=exy[0]; ic[t][4]=exy[1];
    __syncthreads();
    if (t<5){
        float m=0.f;
        for (int bb=0;bb<64;bb++) m += ic[bb][t];
        m *= (1.f/64.f);
        float v=0.f;
        for (int bb=0;bb<64;bb++){ float d=ic[bb][t]-m; v+=d*d; }
        v *= (1.f/64.f);
        mu[t]=m; iv[t]=1.f/sqrtf(v+1e-5f);
    }
    __syncthreads();
    float vn[5];
    #pragma unroll
    for (int c=0;c<5;c++) vn[c] = (ic[t][c]-mu[c])*iv[c]*bn_gamma[c]+bn_beta[c];
    float q0=bc2[0], q1=bc2[1], q2=bc2[2];
    for (int j=0;j<64;j++){
        float hh = b2[j];
        #pragma unroll
        for (int c=0;c<5;c++) hh += vn[c]*w2[c*64+j];
        hh = fmaxf(hh,0.f);
        q0 += hh*wc2[j*3+0]; q1 += hh*wc2[j*3+1]; q2 += hh*wc2[j*3+2];
    }
    dout[448+t*3+0]=q0; dout[448+t*3+1]=q1; dout[448+t*3+2]=q2;
    float m = fmaxf(q0,fmaxf(q1,q2));
    float e0=__expf(q0-m), e1=__expf(q1-m), e2=__expf(q2-m);
    float inv=1.f/(e0+e1+e2);
    dout[832+t*3+0]=e0*inv; dout[832+t*3+1]=e1*inv; dout[832+t*3+2]=e2*inv;
}

extern "C" void kernel_launch(void* const* d_in, const int* in_sizes, int n_in,
                              void* d_out, int out_size, void* d_ws, size_t ws_size,
                              hipStream_t stream)
{
    const float* x     = (const float*)d_in[0];
    const float* y     = (const float*)d_in[1];
    const float* w11_1 = (const float*)d_in[2];
    const float* b11_1 = (const float*)d_in[3];
    const float* w11_2 = (const float*)d_in[4];
    const float* b11_2 = (const float*)d_in[5];
    const float* w12_1 = (const float*)d_in[6];
    const float* b12_1 = (const float*)d_in[7];
    const float* w12_2 = (const float*)d_in[8];
    const float* b12_2 = (const float*)d_in[9];
    const float* wc1   = (const float*)d_in[10];
    const float* bc1   = (const float*)d_in[11];
    const float* bn_g  = (const float*)d_in[12];
    const float* bn_b  = (const float*)d_in[13];
    const float* w2    = (const float*)d_in[14];
    const float* b2    = (const float*)d_in[15];
    const float* wc2   = (const float*)d_in[16];
    const float* bc2   = (const float*)d_in[17];

    float* dout = (float*)d_out;
    float* ws   = (float*)d_ws;
    float* out_x = ws;                       // 1,048,576 floats
    float* out_y = ws + (1u<<20);
    float* resx  = ws + (2u<<20);
    float* resy  = ws + (3u<<20);
    float* resn  = ws + (4u<<20);            // 2*64*256 = 32768
    float* rawn  = resn + 2*NB*NS;           // 32768
    float* mean_part = rawn + 2*NB*NS;       // 64*4*64 = 16384
    float* part3 = mean_part + NB*4*64;      // 64*2*2*3 = 1536

    hipLaunchKernelGGL(k1_fused, dim3(NB*4), dim3(256), 0, stream,
        x,y,w11_1,b11_1,w11_2,b11_2,w12_1,b12_1,w12_2,b12_2,
        out_x,out_y,mean_part);
    hipLaunchKernelGGL(k2_reg, dim3(2*NB), dim3(256), 0, stream,
        out_x,out_y,x,y,resx,resy,resn,rawn,dout);
    hipLaunchKernelGGL(k3_renyi, dim3(NB*4), dim3(256), 0, stream,
        resx,resy,x,y,resn,rawn,part3);
    hipLaunchKernelGGL(k4_final, dim3(1), dim3(64), 0, stream,
        mean_part,part3,wc1,bc1,bn_g,bn_b,w2,b2,wc2,bc2,dout);
}